// Round 4
// baseline (182.534 us; speedup 1.0000x reference)
//
#include <hip/hip_runtime.h>
#include <hip/hip_bf16.h>

#define NODE 1024
#define BS 8
#define XG_K 208   // 192 ki + 1 bias + 15 zero-pad (13 K-windows of 16)

struct alignas(8) bf4 { __hip_bfloat16 a, b, c, d; };
typedef short short8 __attribute__((ext_vector_type(8)));
typedef float f32x16 __attribute__((ext_vector_type(16)));

// ---------------------------------------------------------------------------
// K1: fused  a-row = ne[n]@neT  ->  8x (relu + row-softmax) -> A16 bf16
// block per n; ne staged in LDS with stride 11 (conflict-free for m=tid+256c)
// ---------------------------------------------------------------------------
__global__ __launch_bounds__(256) void k_attn(const float* __restrict__ ne,
                                              const float* __restrict__ t,
                                              const float* __restrict__ nt,
                                              __hip_bfloat16* __restrict__ A16) {
    __shared__ float nel[NODE * 11];
    __shared__ float redm[8][4], reds[8][4];
    int n = blockIdx.x, tid = threadIdx.x;
    int lane = tid & 63, wid = tid >> 6;

    for (int i = tid; i < NODE * 10; i += 256) nel[(i / 10) * 11 + (i % 10)] = ne[i];

    float at[8];
#pragma unroll
    for (int b = 0; b < 8; ++b) {
        float s = 0.f;
#pragma unroll
        for (int j = 0; j < 6; ++j) s += nt[b * 6 + j] * t[b * 6 + j];
        at[b] = s;
    }
    __syncthreads();

    float nr[10];
#pragma unroll
    for (int d = 0; d < 10; ++d) nr[d] = nel[n * 11 + d];

    float v[4];
#pragma unroll
    for (int c = 0; c < 4; ++c) {
        int m = tid + c * 256;
        float s = 0.f;
#pragma unroll
        for (int d = 0; d < 10; ++d) s += nr[d] * nel[m * 11 + d];
        v[c] = s;
    }

#pragma unroll
    for (int b = 0; b < 8; ++b) {
        float u[4], mx = 0.f;   // relu floor: row max >= 0
#pragma unroll
        for (int c = 0; c < 4; ++c) { u[c] = fmaxf(v[c] + at[b], 0.f); mx = fmaxf(mx, u[c]); }
#pragma unroll
        for (int off = 32; off > 0; off >>= 1) mx = fmaxf(mx, __shfl_xor(mx, off));
        if (lane == 0) redm[b][wid] = mx;
        __syncthreads();
        mx = fmaxf(fmaxf(redm[b][0], redm[b][1]), fmaxf(redm[b][2], redm[b][3]));

        float s = 0.f;
#pragma unroll
        for (int c = 0; c < 4; ++c) { u[c] = __expf(u[c] - mx); s += u[c]; }
#pragma unroll
        for (int off = 32; off > 0; off >>= 1) s += __shfl_xor(s, off);
        if (lane == 0) reds[b][wid] = s;
        __syncthreads();
        s = reds[b][0] + reds[b][1] + reds[b][2] + reds[b][3];
        float inv = 1.f / s;

        __hip_bfloat16* dst = A16 + (((size_t)(b << 10) + n) << 10);
#pragma unroll
        for (int c = 0; c < 4; ++c) dst[tid + c * 256] = __float2bfloat16(u[c] * inv);
    }
}

// ---------------------------------------------------------------------------
// K2: x -> xT bf16 [b][f][node] (spmm1 A-operand) AND xg rows [0..63] + bias/pad cols
// ---------------------------------------------------------------------------
__global__ void k_prep(const float* __restrict__ x, __hip_bfloat16* __restrict__ xT,
                       __hip_bfloat16* __restrict__ xg) {
    int b = blockIdx.x >> 4;
    int n0 = (blockIdx.x & 15) * 64;
    __shared__ __hip_bfloat16 T[64][72];
    int tid = threadIdx.x;
    int nloc = tid >> 2, f0 = (tid & 3) * 16;
    size_t row = (size_t)(b << 10) + n0 + nloc;
    {
        const float* src = x + row * 64 + f0;
        __hip_bfloat16* dst = xg + row * XG_K + f0;
#pragma unroll
        for (int j = 0; j < 16; j += 4) {
            float4 vv = *(const float4*)(src + j);
            bf4 o;
            o.a = __float2bfloat16(vv.x); o.b = __float2bfloat16(vv.y);
            o.c = __float2bfloat16(vv.z); o.d = __float2bfloat16(vv.w);
            *(bf4*)(dst + j) = o;
            T[f0 + j][nloc] = o.a; T[f0 + j + 1][nloc] = o.b;
            T[f0 + j + 2][nloc] = o.c; T[f0 + j + 3][nloc] = o.d;
        }
    }
    if (tid < 64) {
        __hip_bfloat16* d2 = xg + ((size_t)(b << 10) + n0 + tid) * XG_K + 192;
        d2[0] = __float2bfloat16(1.0f);
#pragma unroll
        for (int j = 1; j < 16; ++j) d2[j] = __float2bfloat16(0.0f);
    }
    __syncthreads();
    {
        int f = tid >> 2, c0 = (tid & 3) * 16;
        __hip_bfloat16* dst = xT + ((size_t)b * 64 + f) * 1024 + n0 + c0;
#pragma unroll
        for (int j = 0; j < 16; ++j) dst[j] = T[f][c0 + j];
    }
}

// ---------------------------------------------------------------------------
// K3: Wt[d][o][k] = bf16(W[d][k][o]); k=192 -> bp[d][o]; 193..207 -> 0
// ---------------------------------------------------------------------------
__global__ void k_wprep(const float* __restrict__ W, const float* __restrict__ bp,
                        __hip_bfloat16* __restrict__ wt) {
    int d = blockIdx.x;
    __shared__ __hip_bfloat16 T[64 * XG_K];
    int tid = threadIdx.x;
    const float* Wd = W + (size_t)d * 192 * 64;
    for (int i = tid; i < 192 * 64; i += 256) {
        int k = i >> 6, o = i & 63;
        T[o * XG_K + k] = __float2bfloat16(Wd[i]);
    }
    if (tid < 64) {
        T[tid * XG_K + 192] = __float2bfloat16(bp[d * 64 + tid]);
#pragma unroll
        for (int j = 1; j < 16; ++j) T[tid * XG_K + 192 + j] = __float2bfloat16(0.0f);
    }
    __syncthreads();
    __hip_bfloat16* dst = wt + (size_t)d * 64 * XG_K;
    for (int i = tid; i < 64 * XG_K; i += 256) dst[i] = T[i];
}

// ---------------------------------------------------------------------------
// K4/K5: MFMA spmm. D[feat][node] = srcT x A16^T.
// FIRST: xg[.,64..127] = bf16(acc), y1T = bf16(acc) transposed
// !FIRST: xg[.,128..191] = bf16(2*acc - x)
// ---------------------------------------------------------------------------
template<bool FIRST>
__global__ void k_spmm_mfma(const __hip_bfloat16* __restrict__ A16,
                            const __hip_bfloat16* __restrict__ srcT,
                            const float* __restrict__ xres,
                            __hip_bfloat16* __restrict__ xg,
                            __hip_bfloat16* __restrict__ youtT) {
    int b = blockIdx.x >> 5;
    int n0 = (blockIdx.x & 31) * 32;
    int tid = threadIdx.x;
    int fh = tid >> 6;          // wave id: feature half
    int lane = tid & 63;
    int l31 = lane & 31, hi = lane >> 5;

    const __hip_bfloat16* pa = srcT + ((size_t)b * 64 + fh * 32 + l31) * 1024 + hi * 8;
    const __hip_bfloat16* pb = A16 + ((size_t)b << 20) + (size_t)(n0 + l31) * 1024 + hi * 8;

    f32x16 acc0, acc1;
#pragma unroll
    for (int i = 0; i < 16; ++i) { acc0[i] = 0.f; acc1[i] = 0.f; }

    short8 ac[4], bc[4];
#pragma unroll
    for (int j = 0; j < 4; ++j) {
        ac[j] = *(const short8*)(pa + j * 16);
        bc[j] = *(const short8*)(pb + j * 16);
    }
    for (int g = 1; g < 16; ++g) {
        short8 an[4], bn[4];
#pragma unroll
        for (int j = 0; j < 4; ++j) {
            an[j] = *(const short8*)(pa + g * 64 + j * 16);
            bn[j] = *(const short8*)(pb + g * 64 + j * 16);
        }
        acc0 = __builtin_amdgcn_mfma_f32_32x32x16_bf16(ac[0], bc[0], acc0, 0, 0, 0);
        acc1 = __builtin_amdgcn_mfma_f32_32x32x16_bf16(ac[1], bc[1], acc1, 0, 0, 0);
        acc0 = __builtin_amdgcn_mfma_f32_32x32x16_bf16(ac[2], bc[2], acc0, 0, 0, 0);
        acc1 = __builtin_amdgcn_mfma_f32_32x32x16_bf16(ac[3], bc[3], acc1, 0, 0, 0);
#pragma unroll
        for (int j = 0; j < 4; ++j) { ac[j] = an[j]; bc[j] = bn[j]; }
    }
    acc0 = __builtin_amdgcn_mfma_f32_32x32x16_bf16(ac[0], bc[0], acc0, 0, 0, 0);
    acc1 = __builtin_amdgcn_mfma_f32_32x32x16_bf16(ac[1], bc[1], acc1, 0, 0, 0);
    acc0 = __builtin_amdgcn_mfma_f32_32x32x16_bf16(ac[2], bc[2], acc0, 0, 0, 0);
    acc1 = __builtin_amdgcn_mfma_f32_32x32x16_bf16(ac[3], bc[3], acc1, 0, 0, 0);

#pragma unroll
    for (int i = 0; i < 16; ++i) acc0[i] += acc1[i];

    int node = n0 + l31;
    size_t row = (size_t)(b << 10) + node;
    const int base = FIRST ? 64 : 128;
#pragma unroll
    for (int rg = 0; rg < 4; ++rg) {
        int fb = fh * 32 + hi * 4 + rg * 8;
        float vx = acc0[rg * 4], vy = acc0[rg * 4 + 1];
        float vz = acc0[rg * 4 + 2], vw = acc0[rg * 4 + 3];
        if (!FIRST) {
            float4 xv = *(const float4*)(xres + row * 64 + fb);
            vx = 2.f * vx - xv.x; vy = 2.f * vy - xv.y;
            vz = 2.f * vz - xv.z; vw = 2.f * vw - xv.w;
        }
        bf4 o;
        o.a = __float2bfloat16(vx); o.b = __float2bfloat16(vy);
        o.c = __float2bfloat16(vz); o.d = __float2bfloat16(vw);
        *(bf4*)(xg + row * XG_K + base + fb) = o;
    }
    if (FIRST) {
#pragma unroll
        for (int r = 0; r < 16; ++r) {
            int f = fh * 32 + hi * 4 + (r >> 2) * 8 + (r & 3);
            youtT[((size_t)b * 64 + f) * 1024 + node] = __float2bfloat16(acc0[r]);
        }
    }
}

// ---------------------------------------------------------------------------
// K6: out[row,o] = sum_d e[row,d] * ( sum_k Wt[d][o][k] * xg[row][k] )
// one wave per 32-row tile; A-side = Wt rows (o), B-side = xg rows (M).
// D: col=lane&31 = row, reg r -> o = (r&3)+8*(r>>2)+4*hi (+32 for acc1).
// bias rides in K-window 12 (xg[192]=1, Wt[..][192]=bp).
// ---------------------------------------------------------------------------
__global__ __launch_bounds__(64) void k_fuse(const __hip_bfloat16* __restrict__ xg,
                                             const __hip_bfloat16* __restrict__ wt,
                                             const float* __restrict__ ne,
                                             const float* __restrict__ nt,
                                             float* __restrict__ out) {
    int m0 = blockIdx.x * 32;
    int lane = threadIdx.x;
    int l31 = lane & 31, hi = lane >> 5;
    int b = m0 >> 10, n0 = m0 & 1023;
    int n = n0 + l31;

    float e[16];
#pragma unroll
    for (int d = 0; d < 10; ++d) e[d] = ne[n * 10 + d];
#pragma unroll
    for (int d = 0; d < 6; ++d) e[10 + d] = nt[b * 6 + d];

    short8 xf[13];
    const __hip_bfloat16* px = xg + (size_t)(m0 + l31) * XG_K + hi * 8;
#pragma unroll
    for (int w = 0; w < 13; ++w) xf[w] = *(const short8*)(px + w * 16);

    f32x16 acc0, acc1;
#pragma unroll
    for (int i = 0; i < 16; ++i) { acc0[i] = 0.f; acc1[i] = 0.f; }

    const __hip_bfloat16* pw = wt + (size_t)l31 * XG_K + hi * 8;
#pragma unroll
    for (int d = 0; d < 16; ++d) {
        const __hip_bfloat16* pwd = pw + (size_t)d * 64 * XG_K;
        f32x16 z0, z1;
#pragma unroll
        for (int i = 0; i < 16; ++i) { z0[i] = 0.f; z1[i] = 0.f; }
#pragma unroll
        for (int w = 0; w < 13; ++w) {
            short8 a0 = *(const short8*)(pwd + w * 16);
            short8 a1 = *(const short8*)(pwd + 32 * XG_K + w * 16);
            z0 = __builtin_amdgcn_mfma_f32_32x32x16_bf16(a0, xf[w], z0, 0, 0, 0);
            z1 = __builtin_amdgcn_mfma_f32_32x32x16_bf16(a1, xf[w], z1, 0, 0, 0);
        }
        float ed = e[d];
#pragma unroll
        for (int i = 0; i < 16; ++i) { acc0[i] += ed * z0[i]; acc1[i] += ed * z1[i]; }
    }

    float* orow = out + (size_t)(m0 + l31) * 64;
#pragma unroll
    for (int r = 0; r < 16; ++r) {
        int o = (r & 3) + 8 * (r >> 2) + 4 * hi;
        orow[o] = acc0[r];
        orow[o + 32] = acc1[r];
    }
}

// ---------------------------------------------------------------------------
extern "C" void kernel_launch(void* const* d_in, const int* in_sizes, int n_in,
                              void* d_out, int out_size, void* d_ws, size_t ws_size,
                              hipStream_t stream) {
    const float* x  = (const float*)d_in[0];   // [8,1024,64]
    const float* ne = (const float*)d_in[1];   // [1024,10]
    const float* t  = (const float*)d_in[2];   // [8,6]
    const float* nt = (const float*)d_in[3];   // [8,6]
    const float* W  = (const float*)d_in[5];   // [16,3,64,64]
    const float* bp = (const float*)d_in[6];   // [16,64]
    float* out = (float*)d_out;                // [8,1024,64]

    __hip_bfloat16* wsb = (__hip_bfloat16*)d_ws;
    __hip_bfloat16* A16 = wsb;                       // 8,388,608 elems
    __hip_bfloat16* xT  = wsb + 8388608;             //   524,288
    __hip_bfloat16* y1T = wsb + 8912896;             //   524,288
    __hip_bfloat16* xg  = wsb + 9437184;             // 8192*208 = 1,703,936
    __hip_bfloat16* wt  = wsb + 11141120;            // 16*64*208 =  212,992

    k_attn<<<NODE, 256, 0, stream>>>(ne, t, nt, A16);
    k_prep<<<BS * 16, 256, 0, stream>>>(x, xT, xg);
    k_wprep<<<16, 256, 0, stream>>>(W, bp, wt);
    k_spmm_mfma<true ><<<BS * 32, 128, 0, stream>>>(A16, xT,  x, xg, y1T);
    k_spmm_mfma<false><<<BS * 32, 128, 0, stream>>>(A16, y1T, x, xg, nullptr);
    k_fuse<<<BS * (NODE / 32), 64, 0, stream>>>(xg, wt, ne, nt, out);
}

// Round 5
// 131.311 us; speedup vs baseline: 1.3901x; 1.3901x over previous
//
#include <hip/hip_runtime.h>
#include <hip/hip_bf16.h>

#define NODE 1024
#define BS 8
#define XG_K 208   // 192 ki + 1 bias + 15 zero-pad (13 K-windows of 16)

struct alignas(8) bf4 { __hip_bfloat16 a, b, c, d; };
typedef short short8 __attribute__((ext_vector_type(8)));
typedef float f32x16 __attribute__((ext_vector_type(16)));

// ---------------------------------------------------------------------------
// K1: fused  a-row = ne[n]@neT  ->  8x (relu + row-softmax) -> A16 bf16
// ---------------------------------------------------------------------------
__global__ __launch_bounds__(256) void k_attn(const float* __restrict__ ne,
                                              const float* __restrict__ t,
                                              const float* __restrict__ nt,
                                              __hip_bfloat16* __restrict__ A16) {
    __shared__ float nel[NODE * 11];
    __shared__ float redm[8][4], reds[8][4];
    int n = blockIdx.x, tid = threadIdx.x;
    int lane = tid & 63, wid = tid >> 6;

    for (int i = tid; i < NODE * 10; i += 256) nel[(i / 10) * 11 + (i % 10)] = ne[i];

    float at[8];
#pragma unroll
    for (int b = 0; b < 8; ++b) {
        float s = 0.f;
#pragma unroll
        for (int j = 0; j < 6; ++j) s += nt[b * 6 + j] * t[b * 6 + j];
        at[b] = s;
    }
    __syncthreads();

    float nr[10];
#pragma unroll
    for (int d = 0; d < 10; ++d) nr[d] = nel[n * 11 + d];

    float v[4];
#pragma unroll
    for (int c = 0; c < 4; ++c) {
        int m = tid + c * 256;
        float s = 0.f;
#pragma unroll
        for (int d = 0; d < 10; ++d) s += nr[d] * nel[m * 11 + d];
        v[c] = s;
    }

#pragma unroll
    for (int b = 0; b < 8; ++b) {
        float u[4], mx = 0.f;   // relu floor: row max >= 0
#pragma unroll
        for (int c = 0; c < 4; ++c) { u[c] = fmaxf(v[c] + at[b], 0.f); mx = fmaxf(mx, u[c]); }
#pragma unroll
        for (int off = 32; off > 0; off >>= 1) mx = fmaxf(mx, __shfl_xor(mx, off));
        if (lane == 0) redm[b][wid] = mx;
        __syncthreads();
        mx = fmaxf(fmaxf(redm[b][0], redm[b][1]), fmaxf(redm[b][2], redm[b][3]));

        float s = 0.f;
#pragma unroll
        for (int c = 0; c < 4; ++c) { u[c] = __expf(u[c] - mx); s += u[c]; }
#pragma unroll
        for (int off = 32; off > 0; off >>= 1) s += __shfl_xor(s, off);
        if (lane == 0) reds[b][wid] = s;
        __syncthreads();
        s = reds[b][0] + reds[b][1] + reds[b][2] + reds[b][3];
        float inv = 1.f / s;

        __hip_bfloat16* dst = A16 + (((size_t)(b << 10) + n) << 10);
#pragma unroll
        for (int c = 0; c < 4; ++c) dst[tid + c * 256] = __float2bfloat16(u[c] * inv);
    }
}

// ---------------------------------------------------------------------------
// K2: x -> xT bf16 [b][f][node] AND xg rows [0..63] + bias/pad cols
// ---------------------------------------------------------------------------
__global__ void k_prep(const float* __restrict__ x, __hip_bfloat16* __restrict__ xT,
                       __hip_bfloat16* __restrict__ xg) {
    int b = blockIdx.x >> 4;
    int n0 = (blockIdx.x & 15) * 64;
    __shared__ __hip_bfloat16 T[64][72];
    int tid = threadIdx.x;
    int nloc = tid >> 2, f0 = (tid & 3) * 16;
    size_t row = (size_t)(b << 10) + n0 + nloc;
    {
        const float* src = x + row * 64 + f0;
        __hip_bfloat16* dst = xg + row * XG_K + f0;
#pragma unroll
        for (int j = 0; j < 16; j += 4) {
            float4 vv = *(const float4*)(src + j);
            bf4 o;
            o.a = __float2bfloat16(vv.x); o.b = __float2bfloat16(vv.y);
            o.c = __float2bfloat16(vv.z); o.d = __float2bfloat16(vv.w);
            *(bf4*)(dst + j) = o;
            T[f0 + j][nloc] = o.a; T[f0 + j + 1][nloc] = o.b;
            T[f0 + j + 2][nloc] = o.c; T[f0 + j + 3][nloc] = o.d;
        }
    }
    if (tid < 64) {
        __hip_bfloat16* d2 = xg + ((size_t)(b << 10) + n0 + tid) * XG_K + 192;
        d2[0] = __float2bfloat16(1.0f);
#pragma unroll
        for (int j = 1; j < 16; ++j) d2[j] = __float2bfloat16(0.0f);
    }
    __syncthreads();
    {
        int f = tid >> 2, c0 = (tid & 3) * 16;
        __hip_bfloat16* dst = xT + ((size_t)b * 64 + f) * 1024 + n0 + c0;
#pragma unroll
        for (int j = 0; j < 16; ++j) dst[j] = T[f][c0 + j];
    }
}

// ---------------------------------------------------------------------------
// K3: Wt[d][o][k] = bf16(W[d][k][o]); k=192 -> bp[d][o]; 193..207 -> 0
// ---------------------------------------------------------------------------
__global__ void k_wprep(const float* __restrict__ W, const float* __restrict__ bp,
                        __hip_bfloat16* __restrict__ wt) {
    int d = blockIdx.x;
    __shared__ __hip_bfloat16 T[64 * XG_K];
    int tid = threadIdx.x;
    const float* Wd = W + (size_t)d * 192 * 64;
    for (int i = tid; i < 192 * 64; i += 256) {
        int k = i >> 6, o = i & 63;
        T[o * XG_K + k] = __float2bfloat16(Wd[i]);
    }
    if (tid < 64) {
        T[tid * XG_K + 192] = __float2bfloat16(bp[d * 64 + tid]);
#pragma unroll
        for (int j = 1; j < 16; ++j) T[tid * XG_K + 192 + j] = __float2bfloat16(0.0f);
    }
    __syncthreads();
    __hip_bfloat16* dst = wt + (size_t)d * 64 * XG_K;
    for (int i = tid; i < 64 * XG_K; i += 256) dst[i] = T[i];
}

// ---------------------------------------------------------------------------
// K4/K5: MFMA spmm. D[feat][node] = srcT x A16^T.
// ---------------------------------------------------------------------------
template<bool FIRST>
__global__ void k_spmm_mfma(const __hip_bfloat16* __restrict__ A16,
                            const __hip_bfloat16* __restrict__ srcT,
                            const float* __restrict__ xres,
                            __hip_bfloat16* __restrict__ xg,
                            __hip_bfloat16* __restrict__ youtT) {
    int b = blockIdx.x >> 5;
    int n0 = (blockIdx.x & 31) * 32;
    int tid = threadIdx.x;
    int fh = tid >> 6;          // wave id: feature half
    int lane = tid & 63;
    int l31 = lane & 31, hi = lane >> 5;

    const __hip_bfloat16* pa = srcT + ((size_t)b * 64 + fh * 32 + l31) * 1024 + hi * 8;
    const __hip_bfloat16* pb = A16 + ((size_t)b << 20) + (size_t)(n0 + l31) * 1024 + hi * 8;

    f32x16 acc0, acc1;
#pragma unroll
    for (int i = 0; i < 16; ++i) { acc0[i] = 0.f; acc1[i] = 0.f; }

    short8 ac[4], bc[4];
#pragma unroll
    for (int j = 0; j < 4; ++j) {
        ac[j] = *(const short8*)(pa + j * 16);
        bc[j] = *(const short8*)(pb + j * 16);
    }
    for (int g = 1; g < 16; ++g) {
        short8 an[4], bn[4];
#pragma unroll
        for (int j = 0; j < 4; ++j) {
            an[j] = *(const short8*)(pa + g * 64 + j * 16);
            bn[j] = *(const short8*)(pb + g * 64 + j * 16);
        }
        acc0 = __builtin_amdgcn_mfma_f32_32x32x16_bf16(ac[0], bc[0], acc0, 0, 0, 0);
        acc1 = __builtin_amdgcn_mfma_f32_32x32x16_bf16(ac[1], bc[1], acc1, 0, 0, 0);
        acc0 = __builtin_amdgcn_mfma_f32_32x32x16_bf16(ac[2], bc[2], acc0, 0, 0, 0);
        acc1 = __builtin_amdgcn_mfma_f32_32x32x16_bf16(ac[3], bc[3], acc1, 0, 0, 0);
#pragma unroll
        for (int j = 0; j < 4; ++j) { ac[j] = an[j]; bc[j] = bn[j]; }
    }
    acc0 = __builtin_amdgcn_mfma_f32_32x32x16_bf16(ac[0], bc[0], acc0, 0, 0, 0);
    acc1 = __builtin_amdgcn_mfma_f32_32x32x16_bf16(ac[1], bc[1], acc1, 0, 0, 0);
    acc0 = __builtin_amdgcn_mfma_f32_32x32x16_bf16(ac[2], bc[2], acc0, 0, 0, 0);
    acc1 = __builtin_amdgcn_mfma_f32_32x32x16_bf16(ac[3], bc[3], acc1, 0, 0, 0);

#pragma unroll
    for (int i = 0; i < 16; ++i) acc0[i] += acc1[i];

    int node = n0 + l31;
    size_t row = (size_t)(b << 10) + node;
    const int base = FIRST ? 64 : 128;
#pragma unroll
    for (int rg = 0; rg < 4; ++rg) {
        int fb = fh * 32 + hi * 4 + rg * 8;
        float vx = acc0[rg * 4], vy = acc0[rg * 4 + 1];
        float vz = acc0[rg * 4 + 2], vw = acc0[rg * 4 + 3];
        if (!FIRST) {
            float4 xv = *(const float4*)(xres + row * 64 + fb);
            vx = 2.f * vx - xv.x; vy = 2.f * vy - xv.y;
            vz = 2.f * vz - xv.z; vw = 2.f * vw - xv.w;
        }
        bf4 o;
        o.a = __float2bfloat16(vx); o.b = __float2bfloat16(vy);
        o.c = __float2bfloat16(vz); o.d = __float2bfloat16(vw);
        *(bf4*)(xg + row * XG_K + base + fb) = o;
    }
    if (FIRST) {
#pragma unroll
        for (int r = 0; r < 16; ++r) {
            int f = fh * 32 + hi * 4 + (r >> 2) * 8 + (r & 3);
            youtT[((size_t)b * 64 + f) * 1024 + node] = __float2bfloat16(acc0[r]);
        }
    }
}

// ---------------------------------------------------------------------------
// K6 v2: out[row,o] = sum_d e[row,d] * ( sum_k Wt[d][o][k] * xg[row][k] )
// block = 8 waves per 32-row tile; wave w owns d in {2w, 2w+1}.
// Each wave: 4 independent MFMA chains (2 d x 2 o-halves) of 13 MFMAs,
// e-scales in-register, writes fp32 partial to LDS; block tree-reduces.
// bias rides in K-window 12 (xg[192]=1, Wt[..][192]=bp) -> sum_d e_d*bp[d,o].
// ---------------------------------------------------------------------------
__global__ __launch_bounds__(512) void k_fuse(const __hip_bfloat16* __restrict__ xg,
                                              const __hip_bfloat16* __restrict__ wt,
                                              const float* __restrict__ ne,
                                              const float* __restrict__ nt,
                                              float* __restrict__ out) {
    __shared__ float P[8][32][66];   // [wave][row][col] fp32 partials (66: 2-way bank alias, free)
    int m0 = blockIdx.x * 32;
    int tid = threadIdx.x;
    int w = tid >> 6;                // wave id -> d pair {2w, 2w+1}
    int lane = tid & 63;
    int l31 = lane & 31, hi = lane >> 5;
    int b = m0 >> 10;
    int n = (m0 & 1023) + l31;

    int d0 = 2 * w, d1 = 2 * w + 1;
    float e0 = (d0 < 10) ? ne[n * 10 + d0] : nt[b * 6 + (d0 - 10)];
    float e1 = (d1 < 10) ? ne[n * 10 + d1] : nt[b * 6 + (d1 - 10)];

    // B-operand: this tile's xg rows (row = l31, k-window w13, slice hi)
    short8 xf[13];
    const __hip_bfloat16* px = xg + (size_t)(m0 + l31) * XG_K + hi * 8;
#pragma unroll
    for (int k = 0; k < 13; ++k) xf[k] = *(const short8*)(px + k * 16);

    f32x16 z00, z01, z10, z11;
#pragma unroll
    for (int i = 0; i < 16; ++i) { z00[i] = 0.f; z01[i] = 0.f; z10[i] = 0.f; z11[i] = 0.f; }

    // A-operand: Wt[d] rows (o = l31 / l31+32)
    const __hip_bfloat16* pw0 = wt + ((size_t)d0 * 64 + l31) * XG_K + hi * 8;
    const __hip_bfloat16* pw1 = pw0 + (size_t)64 * XG_K;
#pragma unroll
    for (int k = 0; k < 13; ++k) {
        short8 a00 = *(const short8*)(pw0 + k * 16);
        short8 a01 = *(const short8*)(pw0 + (size_t)32 * XG_K + k * 16);
        short8 a10 = *(const short8*)(pw1 + k * 16);
        short8 a11 = *(const short8*)(pw1 + (size_t)32 * XG_K + k * 16);
        z00 = __builtin_amdgcn_mfma_f32_32x32x16_bf16(a00, xf[k], z00, 0, 0, 0);
        z01 = __builtin_amdgcn_mfma_f32_32x32x16_bf16(a01, xf[k], z01, 0, 0, 0);
        z10 = __builtin_amdgcn_mfma_f32_32x32x16_bf16(a10, xf[k], z10, 0, 0, 0);
        z11 = __builtin_amdgcn_mfma_f32_32x32x16_bf16(a11, xf[k], z11, 0, 0, 0);
    }

    // e-scale (e depends only on D-col = l31) and drop partial into LDS
#pragma unroll
    for (int r = 0; r < 16; ++r) {
        int o = (r & 3) + 8 * (r >> 2) + 4 * hi;
        P[w][l31][o]      = e0 * z00[r] + e1 * z10[r];
        P[w][l31][o + 32] = e0 * z01[r] + e1 * z11[r];
    }
    __syncthreads();

    // reduce 8 partials: thread -> (m = tid>>4, 4 cols at o0 = (tid&15)*4)
    int m = tid >> 4, o0 = (tid & 15) * 4;
    float s0 = 0.f, s1 = 0.f, s2 = 0.f, s3 = 0.f;
#pragma unroll
    for (int ww = 0; ww < 8; ++ww) {
        s0 += P[ww][m][o0];
        s1 += P[ww][m][o0 + 1];
        s2 += P[ww][m][o0 + 2];
        s3 += P[ww][m][o0 + 3];
    }
    *(float4*)(out + (size_t)(m0 + m) * 64 + o0) = make_float4(s0, s1, s2, s3);
}

// ---------------------------------------------------------------------------
extern "C" void kernel_launch(void* const* d_in, const int* in_sizes, int n_in,
                              void* d_out, int out_size, void* d_ws, size_t ws_size,
                              hipStream_t stream) {
    const float* x  = (const float*)d_in[0];   // [8,1024,64]
    const float* ne = (const float*)d_in[1];   // [1024,10]
    const float* t  = (const float*)d_in[2];   // [8,6]
    const float* nt = (const float*)d_in[3];   // [8,6]
    const float* W  = (const float*)d_in[5];   // [16,3,64,64]
    const float* bp = (const float*)d_in[6];   // [16,64]
    float* out = (float*)d_out;                // [8,1024,64]

    __hip_bfloat16* wsb = (__hip_bfloat16*)d_ws;
    __hip_bfloat16* A16 = wsb;                       // 8,388,608 elems
    __hip_bfloat16* xT  = wsb + 8388608;             //   524,288
    __hip_bfloat16* y1T = wsb + 8912896;             //   524,288
    __hip_bfloat16* xg  = wsb + 9437184;             // 8192*208 = 1,703,936
    __hip_bfloat16* wt  = wsb + 11141120;            // 16*64*208 =  212,992

    k_attn<<<NODE, 256, 0, stream>>>(ne, t, nt, A16);
    k_prep<<<BS * 16, 256, 0, stream>>>(x, xT, xg);
    k_wprep<<<16, 256, 0, stream>>>(W, bp, wt);
    k_spmm_mfma<true ><<<BS * 32, 128, 0, stream>>>(A16, xT,  x, xg, y1T);
    k_spmm_mfma<false><<<BS * 32, 128, 0, stream>>>(A16, y1T, x, xg, nullptr);
    k_fuse<<<BS * (NODE / 32), 512, 0, stream>>>(xg, wt, ne, nt, out);
}

// Round 6
// 117.224 us; speedup vs baseline: 1.5571x; 1.1202x over previous
//
#include <hip/hip_runtime.h>
#include <hip/hip_bf16.h>

#define NODE 1024
#define BS 8
#define XG_K 208   // 192 ki + 1 bias + 15 zero-pad (13 K-windows of 16)

struct alignas(8) bf4 { __hip_bfloat16 a, b, c, d; };
typedef short short8 __attribute__((ext_vector_type(8)));
typedef float f32x16 __attribute__((ext_vector_type(16)));

// ---------------------------------------------------------------------------
// K1: fused  a-row = ne[n]@neT -> 8x (relu + row-softmax) -> A16 bf16
// v3: one WAVE per row (4 rows/block). No block barriers in the softmax:
// wave-local shfl reductions only. No max-subtract: logits <= ~25 << 88,
// exp(relu(z))/sum == softmax(relu(z)) exactly.
// ---------------------------------------------------------------------------
__global__ __launch_bounds__(256) void k_attn(const float* __restrict__ ne,
                                              const float* __restrict__ t,
                                              const float* __restrict__ nt,
                                              __hip_bfloat16* __restrict__ A16) {
    __shared__ float nel[NODE * 11];
    int tid = threadIdx.x;
    int w = tid >> 6, lane = tid & 63;
    int n = (blockIdx.x << 2) + w;

    for (int i = tid; i < NODE * 10; i += 256) nel[(i / 10) * 11 + (i % 10)] = ne[i];

    float at[8];
#pragma unroll
    for (int b = 0; b < 8; ++b) {
        float s = 0.f;
#pragma unroll
        for (int j = 0; j < 6; ++j) s += nt[b * 6 + j] * t[b * 6 + j];
        at[b] = s;
    }
    __syncthreads();

    float nr[10];
#pragma unroll
    for (int d = 0; d < 10; ++d) nr[d] = nel[n * 11 + d];

    // 16 logits per lane: m = lane + 64j (stride-11 LDS rows -> conflict-free)
    float v[16];
#pragma unroll
    for (int j = 0; j < 16; ++j) {
        const float* row = &nel[(lane + (j << 6)) * 11];
        float s = 0.f;
#pragma unroll
        for (int d = 0; d < 10; ++d) s += nr[d] * row[d];
        v[j] = s;
    }

#pragma unroll
    for (int b = 0; b < 8; ++b) {
        float u[16], s = 0.f;
#pragma unroll
        for (int j = 0; j < 16; ++j) {
            u[j] = __expf(fmaxf(v[j] + at[b], 0.f));
            s += u[j];
        }
#pragma unroll
        for (int off = 32; off > 0; off >>= 1) s += __shfl_xor(s, off);
        float inv = 1.f / s;
        __hip_bfloat16* dst = A16 + (((size_t)(b << 10) + n) << 10);
#pragma unroll
        for (int j = 0; j < 16; ++j) dst[lane + (j << 6)] = __float2bfloat16(u[j] * inv);
    }
}

// ---------------------------------------------------------------------------
// K2 (merged): blocks 0..127  : x -> xT bf16 + xg rows [0..63] + bias/pad
//              blocks 128..143: Wt[d][o][k] = bf16(W[d][k][o]) + bias col
// ---------------------------------------------------------------------------
__global__ __launch_bounds__(256) void k_prepw(const float* __restrict__ x,
                                               const float* __restrict__ W,
                                               const float* __restrict__ bp,
                                               __hip_bfloat16* __restrict__ xT,
                                               __hip_bfloat16* __restrict__ xg,
                                               __hip_bfloat16* __restrict__ wt) {
    __shared__ __hip_bfloat16 sh[64 * XG_K];   // 26.6KB, reused by both branches
    int tid = threadIdx.x;

    if (blockIdx.x < 128) {
        typedef __hip_bfloat16 row72[72];
        row72* T = (row72*)sh;
        int b = blockIdx.x >> 4;
        int n0 = (blockIdx.x & 15) * 64;
        int nloc = tid >> 2, f0 = (tid & 3) * 16;
        size_t row = (size_t)(b << 10) + n0 + nloc;
        {
            const float* src = x + row * 64 + f0;
            __hip_bfloat16* dst = xg + row * XG_K + f0;
#pragma unroll
            for (int j = 0; j < 16; j += 4) {
                float4 vv = *(const float4*)(src + j);
                bf4 o;
                o.a = __float2bfloat16(vv.x); o.b = __float2bfloat16(vv.y);
                o.c = __float2bfloat16(vv.z); o.d = __float2bfloat16(vv.w);
                *(bf4*)(dst + j) = o;
                T[f0 + j][nloc] = o.a; T[f0 + j + 1][nloc] = o.b;
                T[f0 + j + 2][nloc] = o.c; T[f0 + j + 3][nloc] = o.d;
            }
        }
        if (tid < 64) {
            __hip_bfloat16* d2 = xg + ((size_t)(b << 10) + n0 + tid) * XG_K + 192;
            d2[0] = __float2bfloat16(1.0f);
#pragma unroll
            for (int j = 1; j < 16; ++j) d2[j] = __float2bfloat16(0.0f);
        }
        __syncthreads();
        {
            int f = tid >> 2, c0 = (tid & 3) * 16;
            __hip_bfloat16* dst = xT + ((size_t)b * 64 + f) * 1024 + n0 + c0;
#pragma unroll
            for (int j = 0; j < 16; ++j) dst[j] = T[f][c0 + j];
        }
    } else {
        int d = blockIdx.x - 128;
        const float* Wd = W + (size_t)d * 192 * 64;
        for (int i = tid; i < 192 * 64; i += 256) {
            int k = i >> 6, o = i & 63;
            sh[o * XG_K + k] = __float2bfloat16(Wd[i]);
        }
        if (tid < 64) {
            sh[tid * XG_K + 192] = __float2bfloat16(bp[d * 64 + tid]);
#pragma unroll
            for (int j = 1; j < 16; ++j) sh[tid * XG_K + 192 + j] = __float2bfloat16(0.0f);
        }
        __syncthreads();
        __hip_bfloat16* dst = wt + (size_t)d * 64 * XG_K;
        for (int i = tid; i < 64 * XG_K; i += 256) dst[i] = sh[i];
    }
}

// ---------------------------------------------------------------------------
// K3/K4: MFMA spmm, v2. D[feat][node] = srcT x A16^T per (b, 32-node tile).
// 4 waves: (fh = feature half, kh = K half). Each wave does 8 K-groups with
// a 3-slot / 2-deep rolling prefetch; kh=1 partials reduced via LDS (pad 67).
// ---------------------------------------------------------------------------
#define LOADG(slot, g) do {                                                   \
    const __hip_bfloat16* qa = pa + (g) * 64;                                 \
    const __hip_bfloat16* qb = pb + (g) * 64;                                 \
    as[slot][0] = *(const short8*)(qa);      as[slot][1] = *(const short8*)(qa + 16); \
    as[slot][2] = *(const short8*)(qa + 32); as[slot][3] = *(const short8*)(qa + 48); \
    bs[slot][0] = *(const short8*)(qb);      bs[slot][1] = *(const short8*)(qb + 16); \
    bs[slot][2] = *(const short8*)(qb + 32); bs[slot][3] = *(const short8*)(qb + 48); \
} while (0)

template<bool FIRST>
__global__ __launch_bounds__(256) void k_spmm_mfma(const __hip_bfloat16* __restrict__ A16,
                                                   const __hip_bfloat16* __restrict__ srcT,
                                                   const float* __restrict__ xres,
                                                   __hip_bfloat16* __restrict__ xg,
                                                   __hip_bfloat16* __restrict__ youtT) {
    __shared__ float P[2][32][67];   // fp32 partials, stride 67 -> conflict-free
    int b = blockIdx.x >> 5;
    int n0 = (blockIdx.x & 31) << 5;
    int tid = threadIdx.x;
    int wv = tid >> 6, lane = tid & 63;
    int fh = wv & 1, kh = wv >> 1;
    int l31 = lane & 31, hi = lane >> 5;

    const __hip_bfloat16* pa = srcT + ((size_t)b * 64 + fh * 32 + l31) * 1024 + (kh << 9) + hi * 8;
    const __hip_bfloat16* pb = A16 + ((size_t)b << 20) + (size_t)(n0 + l31) * 1024 + (kh << 9) + hi * 8;

    f32x16 acc0, acc1;
#pragma unroll
    for (int i = 0; i < 16; ++i) { acc0[i] = 0.f; acc1[i] = 0.f; }

    short8 as[3][4], bs[3][4];
    LOADG(0, 0);
    LOADG(1, 1);
#pragma unroll
    for (int g = 0; g < 8; ++g) {
        if (g + 2 < 8) { LOADG((g + 2) % 3, g + 2); }
        int cu = g % 3;
        acc0 = __builtin_amdgcn_mfma_f32_32x32x16_bf16(as[cu][0], bs[cu][0], acc0, 0, 0, 0);
        acc1 = __builtin_amdgcn_mfma_f32_32x32x16_bf16(as[cu][1], bs[cu][1], acc1, 0, 0, 0);
        acc0 = __builtin_amdgcn_mfma_f32_32x32x16_bf16(as[cu][2], bs[cu][2], acc0, 0, 0, 0);
        acc1 = __builtin_amdgcn_mfma_f32_32x32x16_bf16(as[cu][3], bs[cu][3], acc1, 0, 0, 0);
    }
#pragma unroll
    for (int i = 0; i < 16; ++i) acc0[i] += acc1[i];

    if (kh == 1) {
#pragma unroll
        for (int r = 0; r < 16; ++r) {
            int f = hi * 4 + (r >> 2) * 8 + (r & 3);   // local feat 0..31
            P[fh][l31][f] = acc0[r];
        }
    }
    __syncthreads();
    if (kh == 0) {
#pragma unroll
        for (int r = 0; r < 16; ++r) {
            int f = hi * 4 + (r >> 2) * 8 + (r & 3);
            acc0[r] += P[fh][l31][f];
        }

        int node = n0 + l31;
        size_t row = (size_t)(b << 10) + node;
        const int base = FIRST ? 64 : 128;
#pragma unroll
        for (int rg = 0; rg < 4; ++rg) {
            int fb = fh * 32 + hi * 4 + rg * 8;
            float vx = acc0[rg * 4], vy = acc0[rg * 4 + 1];
            float vz = acc0[rg * 4 + 2], vw = acc0[rg * 4 + 3];
            if (!FIRST) {
                float4 xv = *(const float4*)(xres + row * 64 + fb);
                vx = 2.f * vx - xv.x; vy = 2.f * vy - xv.y;
                vz = 2.f * vz - xv.z; vw = 2.f * vw - xv.w;
            }
            bf4 o;
            o.a = __float2bfloat16(vx); o.b = __float2bfloat16(vy);
            o.c = __float2bfloat16(vz); o.d = __float2bfloat16(vw);
            *(bf4*)(xg + row * XG_K + base + fb) = o;
        }
        if (FIRST) {
#pragma unroll
            for (int r = 0; r < 16; ++r) {
                int f = fh * 32 + hi * 4 + (r >> 2) * 8 + (r & 3);
                youtT[((size_t)b * 64 + f) * 1024 + node] = __float2bfloat16(acc0[r]);
            }
        }
    }
}

// ---------------------------------------------------------------------------
// K5: out[row,o] = sum_d e[row,d] * ( sum_k Wt[d][o][k] * xg[row][k] )
// 8 waves per 32-row tile; wave w owns d in {2w, 2w+1}; LDS tree-reduce.
// ---------------------------------------------------------------------------
__global__ __launch_bounds__(512) void k_fuse(const __hip_bfloat16* __restrict__ xg,
                                              const __hip_bfloat16* __restrict__ wt,
                                              const float* __restrict__ ne,
                                              const float* __restrict__ nt,
                                              float* __restrict__ out) {
    __shared__ float P[8][32][67];
    int m0 = blockIdx.x * 32;
    int tid = threadIdx.x;
    int w = tid >> 6;
    int lane = tid & 63;
    int l31 = lane & 31, hi = lane >> 5;
    int b = m0 >> 10;
    int n = (m0 & 1023) + l31;

    int d0 = 2 * w, d1 = 2 * w + 1;
    float e0 = (d0 < 10) ? ne[n * 10 + d0] : nt[b * 6 + (d0 - 10)];
    float e1 = (d1 < 10) ? ne[n * 10 + d1] : nt[b * 6 + (d1 - 10)];

    short8 xf[13];
    const __hip_bfloat16* px = xg + (size_t)(m0 + l31) * XG_K + hi * 8;
#pragma unroll
    for (int k = 0; k < 13; ++k) xf[k] = *(const short8*)(px + k * 16);

    f32x16 z00, z01, z10, z11;
#pragma unroll
    for (int i = 0; i < 16; ++i) { z00[i] = 0.f; z01[i] = 0.f; z10[i] = 0.f; z11[i] = 0.f; }

    const __hip_bfloat16* pw0 = wt + ((size_t)d0 * 64 + l31) * XG_K + hi * 8;
    const __hip_bfloat16* pw1 = pw0 + (size_t)64 * XG_K;
#pragma unroll
    for (int k = 0; k < 13; ++k) {
        short8 a00 = *(const short8*)(pw0 + k * 16);
        short8 a01 = *(const short8*)(pw0 + (size_t)32 * XG_K + k * 16);
        short8 a10 = *(const short8*)(pw1 + k * 16);
        short8 a11 = *(const short8*)(pw1 + (size_t)32 * XG_K + k * 16);
        z00 = __builtin_amdgcn_mfma_f32_32x32x16_bf16(a00, xf[k], z00, 0, 0, 0);
        z01 = __builtin_amdgcn_mfma_f32_32x32x16_bf16(a01, xf[k], z01, 0, 0, 0);
        z10 = __builtin_amdgcn_mfma_f32_32x32x16_bf16(a10, xf[k], z10, 0, 0, 0);
        z11 = __builtin_amdgcn_mfma_f32_32x32x16_bf16(a11, xf[k], z11, 0, 0, 0);
    }

#pragma unroll
    for (int r = 0; r < 16; ++r) {
        int o = (r & 3) + 8 * (r >> 2) + 4 * hi;
        P[w][l31][o]      = e0 * z00[r] + e1 * z10[r];
        P[w][l31][o + 32] = e0 * z01[r] + e1 * z11[r];
    }
    __syncthreads();

    int m = tid >> 4, o0 = (tid & 15) * 4;
    float s0 = 0.f, s1 = 0.f, s2 = 0.f, s3 = 0.f;
#pragma unroll
    for (int ww = 0; ww < 8; ++ww) {
        s0 += P[ww][m][o0];
        s1 += P[ww][m][o0 + 1];
        s2 += P[ww][m][o0 + 2];
        s3 += P[ww][m][o0 + 3];
    }
    *(float4*)(out + (size_t)(m0 + m) * 64 + o0) = make_float4(s0, s1, s2, s3);
}

// ---------------------------------------------------------------------------
extern "C" void kernel_launch(void* const* d_in, const int* in_sizes, int n_in,
                              void* d_out, int out_size, void* d_ws, size_t ws_size,
                              hipStream_t stream) {
    const float* x  = (const float*)d_in[0];   // [8,1024,64]
    const float* ne = (const float*)d_in[1];   // [1024,10]
    const float* t  = (const float*)d_in[2];   // [8,6]
    const float* nt = (const float*)d_in[3];   // [8,6]
    const float* W  = (const float*)d_in[5];   // [16,3,64,64]
    const float* bp = (const float*)d_in[6];   // [16,64]
    float* out = (float*)d_out;                // [8,1024,64]

    __hip_bfloat16* wsb = (__hip_bfloat16*)d_ws;
    __hip_bfloat16* A16 = wsb;                       // 8,388,608 elems
    __hip_bfloat16* xT  = wsb + 8388608;             //   524,288
    __hip_bfloat16* y1T = wsb + 8912896;             //   524,288
    __hip_bfloat16* xg  = wsb + 9437184;             // 8192*208 = 1,703,936
    __hip_bfloat16* wt  = wsb + 11141120;            // 16*64*208 =  212,992

    k_attn<<<NODE / 4, 256, 0, stream>>>(ne, t, nt, A16);
    k_prepw<<<144, 256, 0, stream>>>(x, W, bp, xT, xg, wt);
    k_spmm_mfma<true ><<<BS * 32, 256, 0, stream>>>(A16, xT,  x, xg, y1T);
    k_spmm_mfma<false><<<BS * 32, 256, 0, stream>>>(A16, y1T, x, xg, nullptr);
    k_fuse<<<BS * (NODE / 32), 512, 0, stream>>>(xg, wt, ne, nt, out);
}